// Round 14
// baseline (258.946 us; speedup 1.0000x reference)
//
#include <hip/hip_runtime.h>

typedef unsigned int u32;
typedef __fp16 half2_t __attribute__((ext_vector_type(2)));
typedef __fp16 half8_t __attribute__((ext_vector_type(8)));
typedef float  f32x4   __attribute__((ext_vector_type(4)));
typedef int    i32x4   __attribute__((ext_vector_type(4)));

#define DIN 128
#define DH  128
#define SEQL 512
#define NBATCH 256
#define NC  512          // 4*DH fused gate columns
#define TC  64           // timesteps per chunk
#define NCHUNK (SEQL/TC) // 8

#define HOFF 131072              // i8 h dbuf after 2 xgT buffers (2 x 128 B)
#define HF2  (131072 + 256)      // final f16 h for tail (256 B)
#define LDS_TOTAL (131072 + 256 + 256)

__device__ __forceinline__ u32 pk2(float a, float b) {
  half2_t h = __builtin_amdgcn_cvt_pkrtz(a, b);
  return __builtin_bit_cast(u32, h);
}

__device__ __forceinline__ float fexp2(float x) {
#if defined(__has_builtin) && __has_builtin(__builtin_amdgcn_exp2f)
  return __builtin_amdgcn_exp2f(x);
#else
  return __builtin_exp2f(x);
#endif
}

// raw step barrier: publish LDS writes (lgkm only), do NOT drain vmcnt --
// keeps phase-A global loads in flight across recurrence barriers.
__device__ __forceinline__ void step_barrier() {
  asm volatile("s_waitcnt lgkmcnt(0)" ::: "memory");
  __builtin_amdgcn_s_barrier();
  asm volatile("" ::: "memory");
}

#define MF(A, B, C) __builtin_amdgcn_mfma_f32_16x16x32_f16( \
    __builtin_bit_cast(half8_t, A), __builtin_bit_cast(half8_t, B), C, 0, 0, 0)
#define MFI8(A, B, C) __builtin_amdgcn_mfma_i32_16x16x64_i8( \
    __builtin_bit_cast(i32x4, A), __builtin_bit_cast(i32x4, B), C, 0, 0, 0)

// Pack fused x-projection weights into f16-pair column-major image,
// PRE-SCALED by the exp2 conversion constants (i,f,o: -log2e; g: -2log2e).
__global__ void pack_w(const float* __restrict__ x2i, const float* __restrict__ x2f,
                       const float* __restrict__ x2g, const float* __restrict__ x2o,
                       u32* __restrict__ wxT) {
  int idx = blockIdx.x * blockDim.x + threadIdx.x;   // 0..32767
  if (idx >= NC * 64) return;
  int j = idx >> 6, kk = idx & 63;
  int g = j >> 7, jjj = j & 127;
  const float* wx = (g == 0) ? x2i : (g == 1) ? x2f : (g == 2) ? x2g : x2o;
  float s = (g == 2) ? -2.885390082f : -1.442695041f;
  wxT[idx] = pk2(s * wx[(2*kk)*DH + jjj], s * wx[(2*kk+1)*DH + jjj]);
}

// Quantize recurrence weights to i8, per-column scale; dequant scale folds
// 1/(127*127) and the exp2 gate constant.
__global__ void pack_whi8(const float* __restrict__ h2i, const float* __restrict__ h2f,
                          const float* __restrict__ h2g, const float* __restrict__ h2o,
                          u32* __restrict__ whI, float* __restrict__ dqs) {
  int j = blockIdx.x * blockDim.x + threadIdx.x;   // 0..511 fused col
  if (j >= NC) return;
  int g = j >> 7, jj = j & 127;
  const float* wh = (g == 0) ? h2i : (g == 1) ? h2f : (g == 2) ? h2g : h2o;
  float amax = 1e-20f;
  for (int k = 0; k < DH; ++k) amax = fmaxf(amax, fabsf(wh[k*DH + jj]));
  float s = 127.f / amax;
  for (int kk = 0; kk < 32; ++kk) {
    u32 wword = 0;
#pragma unroll
    for (int t = 0; t < 4; ++t) {
      int q = (int)__builtin_rintf(wh[(4*kk + t)*DH + jj] * s);
      wword |= ((u32)(q & 0xFF)) << (8 * t);
    }
    whI[j*32 + kk] = wword;
  }
  dqs[j] = (amax / 16129.f) * ((g == 2) ? -2.885390082f : -1.442695041f);
}

// LDS: xgT[2] dbuf ([col][128 B of t] XOR-swizzled f16) + i8 h dbuf + f16 h.
// Recurrence gate GEMM: mfma_i32_16x16x64_i8 (8 MFMA/wave/step).
// Nonlinearity kg-SPLIT: lane group kg evaluates only gate kg; three parallel
// shfl_xor(16/32/48) gather f,g,o into lanes 0-15 which own the c/h update.
__global__ __launch_bounds__(512, 2)
void lstm_fused(
    const float* __restrict__ x, const u32* __restrict__ wxT,
    const u32* __restrict__ whI, const float* __restrict__ dqs,
    const float* __restrict__ w_out, float* __restrict__ out) {
  extern __shared__ char lds[];

  const int tid = threadIdx.x;
  const int b   = blockIdx.x;
  const int l   = tid & 63, wv = tid >> 6;
  const int kg  = l >> 4, r15 = l & 15;
  const int j   = wv * 16 + r15;   // hidden index this lane owns

  // i8 recurrence B-frags: bi8[g][m] = whI[(g*128+j)*32][m*16+kg*4 ..+4]
  uint4 bi8[4][2];
#pragma unroll
  for (int g = 0; g < 4; ++g) {
    const uint4* wp = (const uint4*)(whI + (g * DH + j) * 32);
    bi8[g][0] = wp[kg];
    bi8[g][1] = wp[4 + kg];
  }
  // own-gate constants (lane group kg handles gate kg)
  const float dqo = dqs[kg * DH + j];
  const float cA = (kg == 2) ? 2.f : 1.f;
  const float cB = (kg == 2) ? -1.f : 0.f;
  // Phase-A B-frags (persistent, 64 VGPRs): this wave's 4 n-tiles
  uint4 bfA[4][4];
#pragma unroll
  for (int nt = 0; nt < 4; ++nt) {
    int n = wv * 64 + nt * 16 + r15;
#pragma unroll
    for (int ko = 0; ko < 4; ++ko)
      bfA[nt][ko] = *(const uint4*)(wxT + n*64 + ko*16 + kg*4);
  }

  if (tid < 64) ((u32*)(lds + HOFF))[tid] = 0u;   // zero both i8 h buffers
  float c = 0.f, lasth = 0.f;
  u32 rdh = HOFF;          // current h (i8[128])
  u32 wrh = HOFF + 128;    // next h
  const float* xb = x + (size_t)b * SEQL * DIN;
  const f32x4 Z  = {0.f, 0.f, 0.f, 0.f};
  const i32x4 ZI = {0, 0, 0, 0};
  __syncthreads();

  // ---- standalone phase A for chunk 0 -> buffer 0 ----
#pragma unroll 1
  for (int tt = 0; tt < 4; ++tt) {
    uint4 afr0[4];
#pragma unroll
    for (int ko = 0; ko < 4; ++ko) {
      const float4* xp = (const float4*)(xb + (size_t)(tt*16 + r15)*DIN + ko*32 + kg*8);
      float4 v0 = xp[0], v1 = xp[1];
      afr0[ko].x = pk2(v0.x, v0.y); afr0[ko].y = pk2(v0.z, v0.w);
      afr0[ko].z = pk2(v1.x, v1.y); afr0[ko].w = pk2(v1.z, v1.w);
    }
#pragma unroll
    for (int nt = 0; nt < 4; ++nt) {
      int n = wv * 64 + nt * 16 + r15;
      f32x4 acc = MF(afr0[0], bfA[nt][0], Z);
      acc = MF(afr0[1], bfA[nt][1], acc);
      acc = MF(afr0[2], bfA[nt][2], acc);
      acc = MF(afr0[3], bfA[nt][3], acc);
      int t0 = tt*16 + kg*4;
      u32 off = (u32)(n*128 + ((t0*2) ^ ((n & 7) << 4)));
      uint2 pw; pw.x = pk2(acc[0], acc[1]); pw.y = pk2(acc[2], acc[3]);
      *(uint2*)(lds + off) = pw;
    }
  }
  __syncthreads();

  int cur = 0;
#pragma unroll 1
  for (int ch = 0; ch < NCHUNK; ++ch) {
    char* xgC = lds + cur * 65536;
    char* xgN = lds + (cur ^ 1) * 65536;
    const bool doA = (ch + 1 < NCHUNK);
    float4 lv[8];    // staged x loads (even m)
    uint4  afr[4];   // f16 A-frags   (built even m, consumed odd m)
    f32x4  aacc;     // A accumulator (odd m, spans 2 steps)

#pragma unroll 1
    for (int m = 0; m < 8; ++m) {
      const int tt = m >> 1;
      // own-gate xg column, timesteps [8m, 8m+8)  (pre-scaled)
      const int cg = kg * DH + j;
      half8_t xh = __builtin_bit_cast(half8_t,
          *(const uint4*)(xgC + cg*128 + ((m*16) ^ ((cg & 7) << 4))));
#pragma unroll
      for (int s8 = 0; s8 < 8; ++s8) {
        // ---- interleaved phase A (chunk ch+1) ----
        if (doA) {
          if ((m & 1) == 0) {
            if (s8 == 0) {
              const float* xr = xb + (size_t)((ch+1)*TC + tt*16 + r15)*DIN + kg*8;
#pragma unroll
              for (int ko = 0; ko < 4; ++ko) {
                const float4* xp = (const float4*)(xr + ko*32);
                lv[2*ko]   = xp[0];
                lv[2*ko+1] = xp[1];
              }
            }
            if (s8 == 2) {
#pragma unroll
              for (int ko = 0; ko < 2; ++ko) {
                float4 v0 = lv[2*ko], v1 = lv[2*ko+1];
                afr[ko].x = pk2(v0.x, v0.y); afr[ko].y = pk2(v0.z, v0.w);
                afr[ko].z = pk2(v1.x, v1.y); afr[ko].w = pk2(v1.z, v1.w);
              }
            }
            if (s8 == 3) {
#pragma unroll
              for (int ko = 2; ko < 4; ++ko) {
                float4 v0 = lv[2*ko], v1 = lv[2*ko+1];
                afr[ko].x = pk2(v0.x, v0.y); afr[ko].y = pk2(v0.z, v0.w);
                afr[ko].z = pk2(v1.x, v1.y); afr[ko].w = pk2(v1.z, v1.w);
              }
            }
          } else {
            const int nt = s8 >> 1;      // compile-time (s8 unrolled)
            if ((s8 & 1) == 0) {
              aacc = MF(afr[1], bfA[nt][1], MF(afr[0], bfA[nt][0], Z));
            } else {
              aacc = MF(afr[3], bfA[nt][3], MF(afr[2], bfA[nt][2], aacc));
              int n = wv * 64 + nt * 16 + r15;
              int t0 = tt*16 + kg*4;
              u32 off = (u32)(n*128 + ((t0*2) ^ ((n & 7) << 4)));
              uint2 pw; pw.x = pk2(aacc[0], aacc[1]); pw.y = pk2(aacc[2], aacc[3]);
              *(uint2*)(xgN + off) = pw;
            }
          }
        }

        // ---- recurrence step (i8 gate GEMM) ----
        uint4 a0 = *(const uint4*)(lds + rdh + kg*16);        // k = kg*16+[0,16)
        uint4 a1 = *(const uint4*)(lds + rdh + 64 + kg*16);   // k = 64+kg*16+[0,16)
        i32x4 aci = MFI8(a0, bi8[0][0], ZI);
        i32x4 acf = MFI8(a0, bi8[1][0], ZI);
        i32x4 acg = MFI8(a0, bi8[2][0], ZI);
        i32x4 aco = MFI8(a0, bi8[3][0], ZI);
        aci = MFI8(a1, bi8[0][1], aci);
        acf = MFI8(a1, bi8[1][1], acf);
        acg = MFI8(a1, bi8[2][1], acg);
        aco = MFI8(a1, bi8[3][1], aco);
        // kg-split: this lane group evaluates only gate kg
        int aown = (kg == 0) ? aci[0] : (kg == 1) ? acf[0]
                 : (kg == 2) ? acg[0] : aco[0];
        float g0 = __builtin_fmaf((float)aown, dqo, (float)xh[s8]);
        float y  = __builtin_amdgcn_rcpf(1.f + fexp2(g0));
        float s  = __builtin_fmaf(cA, y, cB);      // sigma (i,f,o) / tanh (g)
        // gather f,g,o into lanes 0-15 (parallel bijective shuffles)
        float sf_ = __shfl_xor(s, 16, 64);
        float sg_ = __shfl_xor(s, 32, 64);
        float so_ = __shfl_xor(s, 48, 64);
        // lanes 0-15 hold the true (i,f,g,o); others compute bounded garbage
        c = __builtin_fmaf(sf_, c, s * sg_);
        float th = __builtin_fmaf(2.f,
                     __builtin_amdgcn_rcpf(1.f + fexp2(c * -2.885390082f)), -1.f);
        float hval = so_ * th;
        lasth = hval;
        int q = (int)__builtin_rintf(hval * 127.f);   // h in (-1,1): no clamp
        if (l < 16) *(char*)(lds + wrh + j) = (char)q;
        u32 tswap = rdh; rdh = wrh; wrh = tswap;
        step_barrier();
      }
    }
    cur ^= 1;
  }

  // ---- publish exact final h as f16, then tail: out[b][n] = h @ w_out ----
  if (l < 16) *(__fp16*)(lds + HF2 + j * 2) = (__fp16)lasth;
  __syncthreads();
  if (tid < DH) {
    int n = tid;
    const u32* hf = (const u32*)(lds + HF2);   // final h (f16 pairs)
    float acc = 0.f;
#pragma unroll 8
    for (int kk = 0; kk < 64; ++kk) {
      half2_t h2v = __builtin_bit_cast(half2_t, hf[kk]);
      acc = __builtin_fmaf((float)h2v[0], w_out[(2*kk)*DH + n],
            __builtin_fmaf((float)h2v[1], w_out[(2*kk+1)*DH + n], acc));
    }
    out[b * DH + n] = acc;
  }
}

extern "C" void kernel_launch(void* const* d_in, const int* in_sizes, int n_in,
                              void* d_out, int out_size, void* d_ws, size_t ws_size,
                              hipStream_t stream) {
  const float* x    = (const float*)d_in[0];
  const float* x2i  = (const float*)d_in[1];
  const float* x2f  = (const float*)d_in[2];
  const float* x2g  = (const float*)d_in[3];
  const float* x2o  = (const float*)d_in[4];
  const float* h2i  = (const float*)d_in[5];
  const float* h2f  = (const float*)d_in[6];
  const float* h2g  = (const float*)d_in[7];
  const float* h2o  = (const float*)d_in[8];
  const float* wout = (const float*)d_in[9];

  u32*   wxT = (u32*)d_ws;                 // 32768 u32 = 128 KB
  u32*   whI = wxT + NC * 64;              // 16384 u32 =  64 KB
  float* dqs = (float*)(whI + NC * 32);    //   512 f32 =   2 KB

  (void)hipFuncSetAttribute((const void*)lstm_fused,
                            hipFuncAttributeMaxDynamicSharedMemorySize, LDS_TOTAL);

  pack_w<<<64, 512, 0, stream>>>(x2i, x2f, x2g, x2o, wxT);
  pack_whi8<<<1, 512, 0, stream>>>(h2i, h2f, h2g, h2o, whI, dqs);
  lstm_fused<<<NBATCH, 512, LDS_TOTAL, stream>>>(x, wxT, whI, dqs, wout, (float*)d_out);
}